// Round 2
// baseline (437.746 us; speedup 1.0000x reference)
//
#include <hip/hip_runtime.h>
#include <math.h>

#define B_SZ 32
#define L_SZ 4096
#define H_SZ 512
#define S_SPLIT 32
#define CHUNK (L_SZ / S_SPLIT)        /* 128 rows per block */
#define ROWS_PER_WAVE (CHUNK / 4)     /* 32 rows per wave   */

// Pass 1: flash-style online softmax + mix accumulation, single pass over context.
// Each wave owns ROWS_PER_WAVE consecutive rows; lane i owns h = {4i..4i+3, 256+4i..256+4i+3}.
__global__ __launch_bounds__(256, 4)
void attn_pass1(const float* __restrict__ q,        // [B,H]
                const float* __restrict__ ctx,      // [B,L,H]
                float* __restrict__ scores_out,     // [B,L]  (raw scores, = attn slot of d_out)
                float* __restrict__ m_part,         // [B,S]
                float* __restrict__ s_part,         // [B,S]
                float* __restrict__ acc_part)       // [B,S,H]
{
    const int bid   = blockIdx.x;
    const int b     = bid / S_SPLIT;
    const int split = bid % S_SPLIT;
    const int tid   = threadIdx.x;
    const int wave  = tid >> 6;
    const int lane  = tid & 63;

    const float4* qv = (const float4*)(q + (size_t)b * H_SZ);
    const float4 q0 = qv[lane];
    const float4 q1 = qv[64 + lane];

    float  m = -INFINITY;
    float  s = 0.f;
    float4 a0 = make_float4(0.f, 0.f, 0.f, 0.f);
    float4 a1 = make_float4(0.f, 0.f, 0.f, 0.f);

    float my_scores[ROWS_PER_WAVE / 64 + 1];   // score for row==lane (coalesced store later)
    float sc_keep = 0.f;                       // ROWS_PER_WAVE==32: lane<32 keeps row 'lane'

    const int l0 = split * CHUNK + wave * ROWS_PER_WAVE;
    const float* ctx_b = ctx + (size_t)b * L_SZ * H_SZ;
    (void)my_scores;

    #pragma unroll 2
    for (int i = 0; i < ROWS_PER_WAVE; ++i) {
        const int l = l0 + i;
        const float4* cv = (const float4*)(ctx_b + (size_t)l * H_SZ);
        const float4 c0 = cv[lane];
        const float4 c1 = cv[64 + lane];

        float p = q0.x*c0.x + q0.y*c0.y + q0.z*c0.z + q0.w*c0.w
                + q1.x*c1.x + q1.y*c1.y + q1.z*c1.z + q1.w*c1.w;
        #pragma unroll
        for (int off = 32; off >= 1; off >>= 1)
            p += __shfl_xor(p, off, 64);
        const float sc = p;   // all lanes hold full dot

        if (lane == i) sc_keep = sc;   // row i's score kept by lane i (i<32 -> lanes 0..31)

        // reference masks exact zeros to -inf (excluded from softmax)
        if (sc != 0.0f) {
            const float m_new = fmaxf(m, sc);
            const float corr  = __expf(m - m_new);   // exp(-inf)=0 on first row
            const float pw    = __expf(sc - m_new);
            s = s * corr + pw;
            a0.x = a0.x * corr + pw * c0.x;
            a0.y = a0.y * corr + pw * c0.y;
            a0.z = a0.z * corr + pw * c0.z;
            a0.w = a0.w * corr + pw * c0.w;
            a1.x = a1.x * corr + pw * c1.x;
            a1.y = a1.y * corr + pw * c1.y;
            a1.z = a1.z * corr + pw * c1.z;
            a1.w = a1.w * corr + pw * c1.w;
            m = m_new;
        }
    }

    // coalesced raw-score store: lanes 0..31 hold rows l0..l0+31
    if (lane < ROWS_PER_WAVE)
        scores_out[(size_t)b * L_SZ + l0 + lane] = sc_keep;

    // combine 4 waves -> one block partial
    __shared__ float lds_m[4];
    __shared__ float lds_s[4];
    __shared__ float lds_acc[4][H_SZ];
    if (lane == 0) { lds_m[wave] = m; lds_s[wave] = s; }
    float* la = lds_acc[wave];
    *(float4*)(la + 4 * lane)       = a0;
    *(float4*)(la + 256 + 4 * lane) = a1;
    __syncthreads();

    const float mb = fmaxf(fmaxf(lds_m[0], lds_m[1]), fmaxf(lds_m[2], lds_m[3]));
    float sb = 0.f, ac0 = 0.f, ac1 = 0.f;
    #pragma unroll
    for (int w = 0; w < 4; ++w) {
        const float wg = (lds_s[w] > 0.f) ? __expf(lds_m[w] - mb) : 0.f;
        sb  += wg * lds_s[w];
        ac0 += wg * lds_acc[w][tid];
        ac1 += wg * lds_acc[w][tid + 256];
    }
    const int ps = b * S_SPLIT + split;
    if (tid == 0) { m_part[ps] = mb; s_part[ps] = sb; }
    acc_part[(size_t)ps * H_SZ + tid]       = ac0;
    acc_part[(size_t)ps * H_SZ + tid + 256] = ac1;
}

// Pass 2 (one block per batch): combine split partials, finalize attn in-place,
// compute out = tanh([mix, output] @ W^T + b).
__global__ __launch_bounds__(256)
void attn_pass2(const float* __restrict__ q,        // [B,H]
                const float* __restrict__ W,        // [H, 2H] row-major
                const float* __restrict__ bias,     // [H]
                const float* __restrict__ m_part,
                const float* __restrict__ s_part,
                const float* __restrict__ acc_part,
                float* __restrict__ out,            // [B,H]
                float* __restrict__ attn)           // [B,L] (holds raw scores on entry)
{
    const int b   = blockIdx.x;
    const int tid = threadIdx.x;

    __shared__ float mix_s[H_SZ];
    __shared__ float q_s[H_SZ];

    // global running max over splits
    float m = -INFINITY;
    #pragma unroll
    for (int j = 0; j < S_SPLIT; ++j)
        m = fmaxf(m, m_part[b * S_SPLIT + j]);

    // combine: total sum + mix for h = tid, tid+256
    float stot = 0.f, mx0 = 0.f, mx1 = 0.f;
    #pragma unroll
    for (int j = 0; j < S_SPLIT; ++j) {
        const float sj = s_part[b * S_SPLIT + j];
        const float wg = (sj > 0.f) ? __expf(m_part[b * S_SPLIT + j] - m) : 0.f;
        stot += wg * sj;
        const float* ap = acc_part + (size_t)(b * S_SPLIT + j) * H_SZ;
        mx0 += wg * ap[tid];
        mx1 += wg * ap[tid + 256];
    }
    const float inv = (stot > 0.f) ? 1.f / stot : 0.f;
    mix_s[tid]       = mx0 * inv;
    mix_s[tid + 256] = mx1 * inv;
    q_s[tid]         = q[(size_t)b * H_SZ + tid];
    q_s[tid + 256]   = q[(size_t)b * H_SZ + tid + 256];

    // finalize attention weights in-place (scores -> softmax), masked/degenerate -> 0
    for (int l = tid; l < L_SZ; l += 256) {
        const float sc = attn[(size_t)b * L_SZ + l];
        const float a  = (sc != 0.0f) ? __expf(sc - m) * inv : 0.f;
        attn[(size_t)b * L_SZ + l] = a;
    }
    __syncthreads();

    // out[h] = tanh(bias[h] + sum_k mix[k]*W[h,k] + sum_k q[k]*W[h,512+k])
    const int h0 = tid;
    const int h1 = tid + 256;
    const float4* w0 = (const float4*)(W + (size_t)h0 * (2 * H_SZ));
    const float4* w1 = (const float4*)(W + (size_t)h1 * (2 * H_SZ));
    const float4* mixv = (const float4*)mix_s;
    const float4* qv   = (const float4*)q_s;

    float acc0 = bias[h0];
    float acc1 = bias[h1];
    #pragma unroll 4
    for (int k = 0; k < H_SZ / 4; ++k) {
        const float4 mv = mixv[k];
        const float4 a  = w0[k];
        const float4 c  = w1[k];
        acc0 += a.x*mv.x + a.y*mv.y + a.z*mv.z + a.w*mv.w;
        acc1 += c.x*mv.x + c.y*mv.y + c.z*mv.z + c.w*mv.w;
    }
    #pragma unroll 4
    for (int k = 0; k < H_SZ / 4; ++k) {
        const float4 qq = qv[k];
        const float4 a  = w0[H_SZ / 4 + k];
        const float4 c  = w1[H_SZ / 4 + k];
        acc0 += a.x*qq.x + a.y*qq.y + a.z*qq.z + a.w*qq.w;
        acc1 += c.x*qq.x + c.y*qq.y + c.z*qq.z + c.w*qq.w;
    }
    out[(size_t)b * H_SZ + h0] = tanhf(acc0);
    out[(size_t)b * H_SZ + h1] = tanhf(acc1);
}

extern "C" void kernel_launch(void* const* d_in, const int* in_sizes, int n_in,
                              void* d_out, int out_size, void* d_ws, size_t ws_size,
                              hipStream_t stream) {
    const float* q    = (const float*)d_in[0];   // output [B,H]
    const float* ctx  = (const float*)d_in[1];   // context [B,L,H]
    const float* W    = (const float*)d_in[2];   // [H, 2H]
    const float* bias = (const float*)d_in[3];   // [H]

    float* out  = (float*)d_out;                 // [B,H] first
    float* attn = out + B_SZ * H_SZ;             // [B,1,L] second (scores scratch -> attn)

    float* ws       = (float*)d_ws;
    float* m_part   = ws;                                   // B*S
    float* s_part   = ws + B_SZ * S_SPLIT;                  // B*S
    float* acc_part = ws + 2 * B_SZ * S_SPLIT;              // B*S*H  (~2 MiB)

    attn_pass1<<<B_SZ * S_SPLIT, 256, 0, stream>>>(q, ctx, attn, m_part, s_part, acc_part);
    attn_pass2<<<B_SZ, 256, 0, stream>>>(q, W, bias, m_part, s_part, acc_part, out, attn);
}

// Round 3
// 375.769 us; speedup vs baseline: 1.1649x; 1.1649x over previous
//
#include <hip/hip_runtime.h>
#include <math.h>

#define B_SZ 32
#define L_SZ 4096
#define H_SZ 512
#define S_SPLIT 32
#define CHUNK (L_SZ / S_SPLIT)        /* 128 rows per block */
#define ROWS_PER_WAVE (CHUNK / 4)     /* 32 rows per wave   */

// Pass 1: flash-style online softmax + mix accumulation, single pass over context.
// Each wave owns ROWS_PER_WAVE consecutive rows; lane i owns h = {4i..4i+3, 256+4i..256+4i+3}.
__global__ __launch_bounds__(256, 4)
void attn_pass1(const float* __restrict__ q,        // [B,H]
                const float* __restrict__ ctx,      // [B,L,H]
                float* __restrict__ scores_out,     // [B,L]  (raw scores, = attn slot of d_out)
                float* __restrict__ m_part,         // [B,S]
                float* __restrict__ s_part,         // [B,S]
                float* __restrict__ acc_part)       // [B,S,H]
{
    const int bid   = blockIdx.x;
    const int b     = bid / S_SPLIT;
    const int split = bid % S_SPLIT;
    const int tid   = threadIdx.x;
    const int wave  = tid >> 6;
    const int lane  = tid & 63;

    const float4* qv = (const float4*)(q + (size_t)b * H_SZ);
    const float4 q0 = qv[lane];
    const float4 q1 = qv[64 + lane];

    float  m = -INFINITY;
    float  s = 0.f;
    float4 a0 = make_float4(0.f, 0.f, 0.f, 0.f);
    float4 a1 = make_float4(0.f, 0.f, 0.f, 0.f);

    float sc_keep = 0.f;   // ROWS_PER_WAVE==32: lane i keeps row i's score

    const int l0 = split * CHUNK + wave * ROWS_PER_WAVE;
    const float* ctx_b = ctx + (size_t)b * L_SZ * H_SZ;

    #pragma unroll 2
    for (int i = 0; i < ROWS_PER_WAVE; ++i) {
        const int l = l0 + i;
        const float4* cv = (const float4*)(ctx_b + (size_t)l * H_SZ);
        const float4 c0 = cv[lane];
        const float4 c1 = cv[64 + lane];

        float p = q0.x*c0.x + q0.y*c0.y + q0.z*c0.z + q0.w*c0.w
                + q1.x*c1.x + q1.y*c1.y + q1.z*c1.z + q1.w*c1.w;
        #pragma unroll
        for (int off = 32; off >= 1; off >>= 1)
            p += __shfl_xor(p, off, 64);
        const float sc = p;   // all lanes hold full dot

        if (lane == i) sc_keep = sc;

        // reference masks exact zeros to -inf (excluded from softmax)
        if (sc != 0.0f) {
            const float m_new = fmaxf(m, sc);
            const float corr  = __expf(m - m_new);   // exp(-inf)=0 on first row
            const float pw    = __expf(sc - m_new);
            s = s * corr + pw;
            a0.x = a0.x * corr + pw * c0.x;
            a0.y = a0.y * corr + pw * c0.y;
            a0.z = a0.z * corr + pw * c0.z;
            a0.w = a0.w * corr + pw * c0.w;
            a1.x = a1.x * corr + pw * c1.x;
            a1.y = a1.y * corr + pw * c1.y;
            a1.z = a1.z * corr + pw * c1.z;
            a1.w = a1.w * corr + pw * c1.w;
            m = m_new;
        }
    }

    // coalesced raw-score store: lanes 0..31 hold rows l0..l0+31
    if (lane < ROWS_PER_WAVE)
        scores_out[(size_t)b * L_SZ + l0 + lane] = sc_keep;

    // combine 4 waves -> one block partial
    __shared__ float lds_m[4];
    __shared__ float lds_s[4];
    __shared__ float lds_acc[4][H_SZ];
    if (lane == 0) { lds_m[wave] = m; lds_s[wave] = s; }
    float* la = lds_acc[wave];
    *(float4*)(la + 4 * lane)       = a0;
    *(float4*)(la + 256 + 4 * lane) = a1;
    __syncthreads();

    const float mb = fmaxf(fmaxf(lds_m[0], lds_m[1]), fmaxf(lds_m[2], lds_m[3]));
    float sb = 0.f, ac0 = 0.f, ac1 = 0.f;
    #pragma unroll
    for (int w = 0; w < 4; ++w) {
        const float wg = (lds_s[w] > 0.f) ? __expf(lds_m[w] - mb) : 0.f;
        sb  += wg * lds_s[w];
        ac0 += wg * lds_acc[w][tid];
        ac1 += wg * lds_acc[w][tid + 256];
    }
    const int ps = b * S_SPLIT + split;
    if (tid == 0) { m_part[ps] = mb; s_part[ps] = sb; }
    acc_part[(size_t)ps * H_SZ + tid]       = ac0;
    acc_part[(size_t)ps * H_SZ + tid + 256] = ac1;
}

// Pass 2a (one block of 512 per batch): combine split partials -> normalized mix,
// finalize attn in-place (scores -> softmax weights).
__global__ __launch_bounds__(512)
void attn_combine(const float* __restrict__ m_part,
                  const float* __restrict__ s_part,
                  const float* __restrict__ acc_part,
                  float* __restrict__ mix_out,      // [B,H]
                  float* __restrict__ attn)         // [B,L] raw scores on entry
{
    const int b   = blockIdx.x;
    const int tid = threadIdx.x;   // 512 = H

    float m = -INFINITY;
    #pragma unroll
    for (int j = 0; j < S_SPLIT; ++j)
        m = fmaxf(m, m_part[b * S_SPLIT + j]);

    float stot = 0.f, mx = 0.f;
    #pragma unroll
    for (int j = 0; j < S_SPLIT; ++j) {
        const float sj = s_part[b * S_SPLIT + j];
        const float wg = (sj > 0.f) ? __expf(m_part[b * S_SPLIT + j] - m) : 0.f;
        stot += wg * sj;
        mx   += wg * acc_part[(size_t)(b * S_SPLIT + j) * H_SZ + tid];
    }
    const float inv = (stot > 0.f) ? 1.f / stot : 0.f;
    mix_out[(size_t)b * H_SZ + tid] = mx * inv;

    #pragma unroll
    for (int l = tid; l < L_SZ; l += 512) {
        const float sc = attn[(size_t)b * L_SZ + l];
        attn[(size_t)b * L_SZ + l] = (sc != 0.0f) ? __expf(sc - m) * inv : 0.f;
    }
}

// Pass 2b: out = tanh([mix, q] @ W^T + b). One WAVE per output element [b,h]:
// 64 lanes split the 1024-long dot, coalesced float4 W loads, shuffle reduce.
__global__ __launch_bounds__(256)
void attn_gemv(const float* __restrict__ q,         // [B,H]
               const float* __restrict__ W,         // [H, 2H]
               const float* __restrict__ bias,      // [H]
               const float* __restrict__ mix,       // [B,H]
               float* __restrict__ out)             // [B,H]
{
    const int wave = threadIdx.x >> 6;
    const int lane = threadIdx.x & 63;
    const int oi   = blockIdx.x * 4 + wave;     // 0 .. B*H-1
    const int b    = oi >> 9;                   // H = 512
    const int h    = oi & (H_SZ - 1);

    const float4* Wr = (const float4*)(W + (size_t)h * (2 * H_SZ));  // 256 float4
    const float4* mv = (const float4*)(mix + (size_t)b * H_SZ);      // 128 float4
    const float4* qv = (const float4*)(q   + (size_t)b * H_SZ);

    const float4 w0 = Wr[lane];
    const float4 w1 = Wr[64 + lane];
    const float4 w2 = Wr[128 + lane];
    const float4 w3 = Wr[192 + lane];
    const float4 x0 = mv[lane];
    const float4 x1 = mv[64 + lane];
    const float4 y0 = qv[lane];
    const float4 y1 = qv[64 + lane];

    float p = w0.x*x0.x + w0.y*x0.y + w0.z*x0.z + w0.w*x0.w
            + w1.x*x1.x + w1.y*x1.y + w1.z*x1.z + w1.w*x1.w
            + w2.x*y0.x + w2.y*y0.y + w2.z*y0.z + w2.w*y0.w
            + w3.x*y1.x + w3.y*y1.y + w3.z*y1.z + w3.w*y1.w;
    #pragma unroll
    for (int off = 32; off >= 1; off >>= 1)
        p += __shfl_xor(p, off, 64);

    if (lane == 0)
        out[oi] = tanhf(p + bias[h]);
}

extern "C" void kernel_launch(void* const* d_in, const int* in_sizes, int n_in,
                              void* d_out, int out_size, void* d_ws, size_t ws_size,
                              hipStream_t stream) {
    const float* q    = (const float*)d_in[0];   // output [B,H]
    const float* ctx  = (const float*)d_in[1];   // context [B,L,H]
    const float* W    = (const float*)d_in[2];   // [H, 2H]
    const float* bias = (const float*)d_in[3];   // [H]

    float* out  = (float*)d_out;                 // [B,H] first
    float* attn = out + B_SZ * H_SZ;             // [B,1,L] second (scores scratch -> attn)

    float* ws       = (float*)d_ws;
    float* m_part   = ws;                                       // B*S
    float* s_part   = ws + B_SZ * S_SPLIT;                      // B*S
    float* acc_part = ws + 2 * B_SZ * S_SPLIT;                  // B*S*H (~2 MiB)
    float* mix      = acc_part + (size_t)B_SZ * S_SPLIT * H_SZ; // B*H

    attn_pass1<<<B_SZ * S_SPLIT, 256, 0, stream>>>(q, ctx, attn, m_part, s_part, acc_part);
    attn_combine<<<B_SZ, 512, 0, stream>>>(m_part, s_part, acc_part, mix, attn);
    attn_gemv<<<(B_SZ * H_SZ) / 4, 256, 0, stream>>>(q, W, bias, mix, out);
}